// Round 6
// baseline (41.169 us; speedup 1.0000x reference)
//
#include <hip/hip_runtime.h>
#include <hip/hip_bf16.h>
#include <math.h>

// CBOW negative-sampling loss, collapsed:
//   out = -( (1/B) * sum_b [ logsig(dot(emb_w[target[b]], c_b))
//                          + sum_k logsig(dot(emb_w[noise[b,k]], c_b)) ] )
//   c_b = mean_w ctx_w[context[b,w]]
// V=100000, D=128, B=16384, W=10, K=10.
//
// R6: main body = R2/R4 proven shape (16 lanes/row, 4 rows/wave, int2 index
// loads, 32-bit shift addressing). Main is at the random-gather HBM floor
// (~3.2 TB/s for 84 MB unique 512B rows; R2/R3/R5 all plateau at ~26 us).
// Remaining overhead was kernel2 + inter-kernel gap (~5 us). Fuse the final
// reduce FENCE-FREE (R4's per-block __threadfence = L2 writeback x1024 was
// the 2x regression):
//   - partial written via relaxed agent-scope atomicExch (no cache ops),
//   - s_waitcnt vmcnt(0) = wait own ack only, then done-counter atomicAdd,
//   - last block reads partials with relaxed agent-scope atomic loads,
//     fixed index order -> bitwise deterministic.

#define CBOW_B 16384
#define CBOW_W 10
#define CBOW_K 10
#define CBOW_D 128
#define ROWS_PER_BLOCK 16
#define NBLOCKS (CBOW_B / ROWS_PER_BLOCK)   // 1024

__device__ __forceinline__ float log_sigmoid(float x) {
    const float t = __expf(-fabsf(x));
    return fminf(x, 0.0f) - __logf(1.0f + t);
}

__global__ __launch_bounds__(256) void cbow_fused(
    const int* __restrict__ context,   // [B, W]
    const int* __restrict__ target,    // [B]
    const int* __restrict__ noise,     // [B, K]
    const float* __restrict__ emb_w,   // [V, D]
    const float* __restrict__ ctx_w,   // [V, D]
    float* __restrict__ block_sums,    // [NBLOCKS] in d_ws
    int* __restrict__ done_count,      // [1] in d_ws, zeroed per call
    float* __restrict__ out)           // [1]
{
    const int wave = threadIdx.x >> 6;  // 0..3
    const int lane = threadIdx.x & 63;
    const int grp  = lane >> 4;         // 0..3: batch row within wave
    const int sub  = lane & 15;         // lane within 16-lane group
    const int b = blockIdx.x * ROWS_PER_BLOCK + wave * 4 + grp;
    const unsigned elem = sub * 8u;     // floats [elem, elem+8) of D=128

    // ---- vector index loads (40 B rows are 8 B aligned -> int2) ----
    const int2* cI = reinterpret_cast<const int2*>(&context[b * CBOW_W]);
    const int2 c01 = cI[0], c23 = cI[1], c45 = cI[2], c67 = cI[3], c89 = cI[4];
    const int2* nI = reinterpret_cast<const int2*>(&noise[b * CBOW_K]);
    const int2 n01 = nI[0], n23 = nI[1], n45 = nI[2], n67 = nI[3], n89 = nI[4];
    const int tgt = target[b];

    // ---- context mean-pool (8 floats/lane); 32-bit gather offsets ----
    float c0x=0,c0y=0,c0z=0,c0w=0, c1x=0,c1y=0,c1z=0,c1w=0;
    #define CBOW_ACC(IDX) {                                                    \
        const float4* p = reinterpret_cast<const float4*>(                     \
            ctx_w + (((unsigned)(IDX) << 7) + elem));                          \
        const float4 r0 = p[0];                                                \
        const float4 r1 = p[1];                                                \
        c0x += r0.x; c0y += r0.y; c0z += r0.z; c0w += r0.w;                    \
        c1x += r1.x; c1y += r1.y; c1z += r1.z; c1w += r1.w; }
    CBOW_ACC(c01.x) CBOW_ACC(c01.y) CBOW_ACC(c23.x) CBOW_ACC(c23.y)
    CBOW_ACC(c45.x) CBOW_ACC(c45.y) CBOW_ACC(c67.x) CBOW_ACC(c67.y)
    CBOW_ACC(c89.x) CBOW_ACC(c89.y)
    #undef CBOW_ACC
    const float inv = 1.0f / CBOW_W;
    c0x*=inv; c0y*=inv; c0z*=inv; c0w*=inv;
    c1x*=inv; c1y*=inv; c1z*=inv; c1w*=inv;

    // ---- positive + negative scores ----
    float sum = 0.0f;
    #define CBOW_DOT(IDX) {                                                    \
        const float4* p = reinterpret_cast<const float4*>(                     \
            emb_w + (((unsigned)(IDX) << 7) + elem));                          \
        const float4 r0 = p[0];                                                \
        const float4 r1 = p[1];                                                \
        float d = c0x*r0.x + c0y*r0.y + c0z*r0.z + c0w*r0.w                    \
                + c1x*r1.x + c1y*r1.y + c1z*r1.z + c1w*r1.w;                   \
        d += __shfl_xor(d, 1, 64);                                             \
        d += __shfl_xor(d, 2, 64);                                             \
        d += __shfl_xor(d, 4, 64);                                             \
        d += __shfl_xor(d, 8, 64);                                             \
        sum += log_sigmoid(d); }
    CBOW_DOT(tgt)
    CBOW_DOT(n01.x) CBOW_DOT(n01.y) CBOW_DOT(n23.x) CBOW_DOT(n23.y)
    CBOW_DOT(n45.x) CBOW_DOT(n45.y) CBOW_DOT(n67.x) CBOW_DOT(n67.y)
    CBOW_DOT(n89.x) CBOW_DOT(n89.y)
    #undef CBOW_DOT

    // ---- combine the 4 groups of this wave ----
    sum += __shfl_xor(sum, 16, 64);
    sum += __shfl_xor(sum, 32, 64);     // every lane holds the wave total

    // ---- per-block partial, fence-free last-block-done reduce ----
    __shared__ float wsum[4];
    __shared__ int is_last;
    if (lane == 0) wsum[wave] = sum;
    __syncthreads();
    if (threadIdx.x == 0) {
        const float partial = wsum[0] + wsum[1] + wsum[2] + wsum[3];
        // relaxed agent-scope atomic: value travels to the device coherence
        // point with the instruction itself — no L2 writeback needed.
        atomicExch(&block_sums[blockIdx.x], partial);
        // wait for OUR exch ack only (cheap), so the counter increment below
        // cannot be observed before our partial is globally visible.
        asm volatile("s_waitcnt vmcnt(0)" ::: "memory");
        const int old = atomicAdd(done_count, 1);    // device-scope [m20]
        is_last = (old == NBLOCKS - 1);
    }
    __syncthreads();
    if (!is_last) return;

    // last block: all partials are at the coherence point; read them with
    // relaxed agent-scope atomic loads (bypass L1/L2 staleness), fixed order.
    double s = 0.0;
    for (int i = threadIdx.x; i < NBLOCKS; i += 256) {
        const float p = __hip_atomic_load(&block_sums[i], __ATOMIC_RELAXED,
                                          __HIP_MEMORY_SCOPE_AGENT);
        s += (double)p;
    }
    __shared__ double sh[256];
    sh[threadIdx.x] = s;
    __syncthreads();
    #pragma unroll
    for (int stride = 128; stride >= 1; stride >>= 1) {
        if (threadIdx.x < stride) sh[threadIdx.x] += sh[threadIdx.x + stride];
        __syncthreads();
    }
    if (threadIdx.x == 0) {
        out[0] = (float)(-sh[0] / (double)CBOW_B);
    }
}

extern "C" void kernel_launch(void* const* d_in, const int* in_sizes, int n_in,
                              void* d_out, int out_size, void* d_ws, size_t ws_size,
                              hipStream_t stream) {
    const int*   context = (const int*)d_in[0];   // [B, W]
    const int*   target  = (const int*)d_in[1];   // [B]
    const int*   noise   = (const int*)d_in[2];   // [B, K]
    const float* emb_w   = (const float*)d_in[3]; // [V, D]
    const float* ctx_w   = (const float*)d_in[4]; // [V, D]
    float*       out     = (float*)d_out;
    float*       block_sums = (float*)d_ws;                 // NBLOCKS floats
    int*         done_count = (int*)d_ws + NBLOCKS;         // 1 int

    hipMemsetAsync(done_count, 0, sizeof(int), stream);     // graph-capture-legal
    cbow_fused<<<NBLOCKS, 256, 0, stream>>>(context, target, noise, emb_w, ctx_w,
                                            block_sums, done_count, out);
}

// Round 7
// 39.497 us; speedup vs baseline: 1.0423x; 1.0423x over previous
//
#include <hip/hip_runtime.h>
#include <hip/hip_bf16.h>
#include <math.h>

// CBOW negative-sampling loss, collapsed:
//   out = -( (1/B) * sum_b [ logsig(dot(emb_w[target[b]], c_b))
//                          + sum_k logsig(dot(emb_w[noise[b,k]], c_b)) ] )
//   c_b = mean_w ctx_w[context[b,w]]
// V=100000, D=128, B=16384, W=10, K=10.
//
// R7: body = proven R2 shape (16 lanes/row, 4 rows/wave, int2 index loads,
// 32-bit shift addressing; main is at the scattered-512B gather floor,
// ~3.2 TB/s on 84 MB compulsory HBM). Epilogue = ONE u64 atomicAdd per
// block: fixed-point partial (scale 2^32, bias 2^41 so addend > 0) packed
// with a block counter in bits [52:63]. Integer adds commute -> bitwise
// deterministic; the returned `old` both signals "last block" and already
// holds the payload sum (no readback, no fence, no second round trip).
// R4 lesson: per-block __threadfence = L2 writeback x1024 (2x regression).
// R6 lesson: even fence-free exch+wait+add epilogue costs ~12 us.

#define CBOW_B 16384
#define CBOW_W 10
#define CBOW_K 10
#define CBOW_D 128
#define ROWS_PER_BLOCK 16
#define NBLOCKS (CBOW_B / ROWS_PER_BLOCK)   // 1024

#define FIX_SCALE 4294967296.0              // 2^32
#define FIX_BIAS  (1ULL << 41)              // > max |partial|*2^32 (~2^39)
#define CNT_SHIFT 52                        // payload sum < 3*2^50 < 2^52

__device__ __forceinline__ float log_sigmoid(float x) {
    const float t = __expf(-fabsf(x));
    return fminf(x, 0.0f) - __logf(1.0f + t);
}

__global__ __launch_bounds__(256) void cbow_fused(
    const int* __restrict__ context,   // [B, W]
    const int* __restrict__ target,    // [B]
    const int* __restrict__ noise,     // [B, K]
    const float* __restrict__ emb_w,   // [V, D]
    const float* __restrict__ ctx_w,   // [V, D]
    unsigned long long* __restrict__ acc,  // [1] in d_ws, zeroed per call
    float* __restrict__ out)           // [1]
{
    const int wave = threadIdx.x >> 6;  // 0..3
    const int lane = threadIdx.x & 63;
    const int grp  = lane >> 4;         // 0..3: batch row within wave
    const int sub  = lane & 15;         // lane within 16-lane group
    const int b = blockIdx.x * ROWS_PER_BLOCK + wave * 4 + grp;
    const unsigned elem = sub * 8u;     // floats [elem, elem+8) of D=128

    // ---- vector index loads (40 B rows are 8 B aligned -> int2) ----
    const int2* cI = reinterpret_cast<const int2*>(&context[b * CBOW_W]);
    const int2 c01 = cI[0], c23 = cI[1], c45 = cI[2], c67 = cI[3], c89 = cI[4];
    const int2* nI = reinterpret_cast<const int2*>(&noise[b * CBOW_K]);
    const int2 n01 = nI[0], n23 = nI[1], n45 = nI[2], n67 = nI[3], n89 = nI[4];
    const int tgt = target[b];

    // ---- context mean-pool (8 floats/lane); 32-bit gather offsets ----
    float c0x=0,c0y=0,c0z=0,c0w=0, c1x=0,c1y=0,c1z=0,c1w=0;
    #define CBOW_ACC(IDX) {                                                    \
        const float4* p = reinterpret_cast<const float4*>(                     \
            ctx_w + (((unsigned)(IDX) << 7) + elem));                          \
        const float4 r0 = p[0];                                                \
        const float4 r1 = p[1];                                                \
        c0x += r0.x; c0y += r0.y; c0z += r0.z; c0w += r0.w;                    \
        c1x += r1.x; c1y += r1.y; c1z += r1.z; c1w += r1.w; }
    CBOW_ACC(c01.x) CBOW_ACC(c01.y) CBOW_ACC(c23.x) CBOW_ACC(c23.y)
    CBOW_ACC(c45.x) CBOW_ACC(c45.y) CBOW_ACC(c67.x) CBOW_ACC(c67.y)
    CBOW_ACC(c89.x) CBOW_ACC(c89.y)
    #undef CBOW_ACC
    const float inv = 1.0f / CBOW_W;
    c0x*=inv; c0y*=inv; c0z*=inv; c0w*=inv;
    c1x*=inv; c1y*=inv; c1z*=inv; c1w*=inv;

    // ---- positive + negative scores ----
    float sum = 0.0f;
    #define CBOW_DOT(IDX) {                                                    \
        const float4* p = reinterpret_cast<const float4*>(                     \
            emb_w + (((unsigned)(IDX) << 7) + elem));                          \
        const float4 r0 = p[0];                                                \
        const float4 r1 = p[1];                                                \
        float d = c0x*r0.x + c0y*r0.y + c0z*r0.z + c0w*r0.w                    \
                + c1x*r1.x + c1y*r1.y + c1z*r1.z + c1w*r1.w;                   \
        d += __shfl_xor(d, 1, 64);                                             \
        d += __shfl_xor(d, 2, 64);                                             \
        d += __shfl_xor(d, 4, 64);                                             \
        d += __shfl_xor(d, 8, 64);                                             \
        sum += log_sigmoid(d); }
    CBOW_DOT(tgt)
    CBOW_DOT(n01.x) CBOW_DOT(n01.y) CBOW_DOT(n23.x) CBOW_DOT(n23.y)
    CBOW_DOT(n45.x) CBOW_DOT(n45.y) CBOW_DOT(n67.x) CBOW_DOT(n67.y)
    CBOW_DOT(n89.x) CBOW_DOT(n89.y)
    #undef CBOW_DOT

    // ---- combine the 4 groups of this wave ----
    sum += __shfl_xor(sum, 16, 64);
    sum += __shfl_xor(sum, 32, 64);     // every lane holds the wave total

    // ---- block partial -> ONE packed u64 atomicAdd ----
    __shared__ float wsum[4];
    if (lane == 0) wsum[wave] = sum;
    __syncthreads();
    if (threadIdx.x == 0) {
        const float partial = wsum[0] + wsum[1] + wsum[2] + wsum[3];
        const long long fx = llrint((double)partial * FIX_SCALE);
        const unsigned long long payload = (unsigned long long)(fx + (long long)FIX_BIAS);
        const unsigned long long add = payload + (1ULL << CNT_SHIFT);
        const unsigned long long old = atomicAdd(acc, add);   // device-scope RMW
        if ((old >> CNT_SHIFT) == (unsigned long long)(NBLOCKS - 1)) {
            // we're last: old's payload field already holds the other 1023
            // payloads; add our own, un-bias, convert.
            const unsigned long long mask = (1ULL << CNT_SHIFT) - 1;
            const unsigned long long tot_payload = (old & mask) + payload;
            const long long tot_fx =
                (long long)(tot_payload - (unsigned long long)NBLOCKS * FIX_BIAS);
            const double s = (double)tot_fx / FIX_SCALE;
            out[0] = (float)(-s / (double)CBOW_B);
        }
    }
}

extern "C" void kernel_launch(void* const* d_in, const int* in_sizes, int n_in,
                              void* d_out, int out_size, void* d_ws, size_t ws_size,
                              hipStream_t stream) {
    const int*   context = (const int*)d_in[0];   // [B, W]
    const int*   target  = (const int*)d_in[1];   // [B]
    const int*   noise   = (const int*)d_in[2];   // [B, K]
    const float* emb_w   = (const float*)d_in[3]; // [V, D]
    const float* ctx_w   = (const float*)d_in[4]; // [V, D]
    float*       out     = (float*)d_out;
    unsigned long long* acc = (unsigned long long*)d_ws;    // 8 B

    hipMemsetAsync(acc, 0, sizeof(unsigned long long), stream);  // graph-legal
    cbow_fused<<<NBLOCKS, 256, 0, stream>>>(context, target, noise, emb_w, ctx_w,
                                            acc, out);
}

// Round 8
// 32.663 us; speedup vs baseline: 1.2604x; 1.2092x over previous
//
#include <hip/hip_runtime.h>
#include <hip/hip_bf16.h>
#include <math.h>

// CBOW negative-sampling loss, collapsed:
//   out = -( (1/B) * sum_b [ logsig(dot(emb_w[target[b]], c_b))
//                          + sum_k logsig(dot(emb_w[noise[b,k]], c_b)) ] )
//   c_b = mean_w ctx_w[context[b,w]]
// V=100000, D=128, B=16384, W=10, K=10.
//
// R8 = champion config: R2 two-kernel structure (16 lanes/row, 4 rows/wave,
// 1024 blocks; 32.1 us proven) + safe trims from R3/R4 (int2 index loads,
// 32-bit shift gather addressing).
// Fusion post-mortems: R4 per-block __threadfence = L2 writeback x1024 (2x
// regression); R6 fence-free exch+wait+add epilogue ~12 us; R7 single packed
// u64 RMW still ~7 us worse than two kernels — 1024 bursty device-scope RMWs
// on one line serialize at ~10 ns each. Two-kernel overhead ~3-4 us is the
// cheapest completion mechanism on gfx950.
// Body is at the gathered-byte path floor (~176 MB served at ~6.5 TB/s from
// LLC/HBM alike; cold==warm timing rules out HBM-BW as the limit; R5's deep
// MLP null rules out latency).

#define CBOW_B 16384
#define CBOW_W 10
#define CBOW_K 10
#define CBOW_D 128
#define ROWS_PER_BLOCK 16
#define NBLOCKS (CBOW_B / ROWS_PER_BLOCK)   // 1024

__device__ __forceinline__ float log_sigmoid(float x) {
    const float t = __expf(-fabsf(x));
    return fminf(x, 0.0f) - __logf(1.0f + t);
}

__global__ __launch_bounds__(256) void cbow_main(
    const int* __restrict__ context,   // [B, W]
    const int* __restrict__ target,    // [B]
    const int* __restrict__ noise,     // [B, K]
    const float* __restrict__ emb_w,   // [V, D]
    const float* __restrict__ ctx_w,   // [V, D]
    float* __restrict__ block_sums)    // [NBLOCKS]
{
    const int wave = threadIdx.x >> 6;  // 0..3
    const int lane = threadIdx.x & 63;
    const int grp  = lane >> 4;         // 0..3: batch row within wave
    const int sub  = lane & 15;         // lane within 16-lane group
    const int b = blockIdx.x * ROWS_PER_BLOCK + wave * 4 + grp;
    const unsigned elem = sub * 8u;     // floats [elem, elem+8) of D=128

    // ---- vector index loads (40 B rows are 8 B aligned -> int2) ----
    const int2* cI = reinterpret_cast<const int2*>(&context[b * CBOW_W]);
    const int2 c01 = cI[0], c23 = cI[1], c45 = cI[2], c67 = cI[3], c89 = cI[4];
    const int2* nI = reinterpret_cast<const int2*>(&noise[b * CBOW_K]);
    const int2 n01 = nI[0], n23 = nI[1], n45 = nI[2], n67 = nI[3], n89 = nI[4];
    const int tgt = target[b];

    // ---- context mean-pool (8 floats/lane); 32-bit gather offsets ----
    float c0x=0,c0y=0,c0z=0,c0w=0, c1x=0,c1y=0,c1z=0,c1w=0;
    #define CBOW_ACC(IDX) {                                                    \
        const float4* p = reinterpret_cast<const float4*>(                     \
            ctx_w + (((unsigned)(IDX) << 7) + elem));                          \
        const float4 r0 = p[0];                                                \
        const float4 r1 = p[1];                                                \
        c0x += r0.x; c0y += r0.y; c0z += r0.z; c0w += r0.w;                    \
        c1x += r1.x; c1y += r1.y; c1z += r1.z; c1w += r1.w; }
    CBOW_ACC(c01.x) CBOW_ACC(c01.y) CBOW_ACC(c23.x) CBOW_ACC(c23.y)
    CBOW_ACC(c45.x) CBOW_ACC(c45.y) CBOW_ACC(c67.x) CBOW_ACC(c67.y)
    CBOW_ACC(c89.x) CBOW_ACC(c89.y)
    #undef CBOW_ACC
    const float inv = 1.0f / CBOW_W;
    c0x*=inv; c0y*=inv; c0z*=inv; c0w*=inv;
    c1x*=inv; c1y*=inv; c1z*=inv; c1w*=inv;

    // ---- positive + negative scores ----
    float sum = 0.0f;
    #define CBOW_DOT(IDX) {                                                    \
        const float4* p = reinterpret_cast<const float4*>(                     \
            emb_w + (((unsigned)(IDX) << 7) + elem));                          \
        const float4 r0 = p[0];                                                \
        const float4 r1 = p[1];                                                \
        float d = c0x*r0.x + c0y*r0.y + c0z*r0.z + c0w*r0.w                    \
                + c1x*r1.x + c1y*r1.y + c1z*r1.z + c1w*r1.w;                   \
        d += __shfl_xor(d, 1, 64);                                             \
        d += __shfl_xor(d, 2, 64);                                             \
        d += __shfl_xor(d, 4, 64);                                             \
        d += __shfl_xor(d, 8, 64);                                             \
        sum += log_sigmoid(d); }
    CBOW_DOT(tgt)
    CBOW_DOT(n01.x) CBOW_DOT(n01.y) CBOW_DOT(n23.x) CBOW_DOT(n23.y)
    CBOW_DOT(n45.x) CBOW_DOT(n45.y) CBOW_DOT(n67.x) CBOW_DOT(n67.y)
    CBOW_DOT(n89.x) CBOW_DOT(n89.y)
    #undef CBOW_DOT

    // ---- combine the 4 groups of this wave ----
    sum += __shfl_xor(sum, 16, 64);
    sum += __shfl_xor(sum, 32, 64);     // every lane holds the wave total

    // ---- per-block partial sum (deterministic; no atomics) ----
    __shared__ float wsum[4];
    if (lane == 0) wsum[wave] = sum;
    __syncthreads();
    if (threadIdx.x == 0) {
        block_sums[blockIdx.x] = wsum[0] + wsum[1] + wsum[2] + wsum[3];
    }
}

__global__ __launch_bounds__(256) void cbow_finish(
    const float* __restrict__ block_sums, float* __restrict__ out)
{
    __shared__ double sh[256];
    double s = 0.0;
    for (int i = threadIdx.x; i < NBLOCKS; i += 256) s += (double)block_sums[i];
    sh[threadIdx.x] = s;
    __syncthreads();
    #pragma unroll
    for (int stride = 128; stride >= 1; stride >>= 1) {
        if (threadIdx.x < stride) sh[threadIdx.x] += sh[threadIdx.x + stride];
        __syncthreads();
    }
    if (threadIdx.x == 0) {
        out[0] = (float)(-sh[0] / (double)CBOW_B);
    }
}

extern "C" void kernel_launch(void* const* d_in, const int* in_sizes, int n_in,
                              void* d_out, int out_size, void* d_ws, size_t ws_size,
                              hipStream_t stream) {
    const int*   context = (const int*)d_in[0];   // [B, W]
    const int*   target  = (const int*)d_in[1];   // [B]
    const int*   noise   = (const int*)d_in[2];   // [B, K]
    const float* emb_w   = (const float*)d_in[3]; // [V, D]
    const float* ctx_w   = (const float*)d_in[4]; // [V, D]
    float*       out     = (float*)d_out;
    float*       block_sums = (float*)d_ws;       // NBLOCKS floats = 4 KiB

    cbow_main<<<NBLOCKS, 256, 0, stream>>>(context, target, noise, emb_w, ctx_w,
                                           block_sums);
    cbow_finish<<<1, 256, 0, stream>>>(block_sums, out);
}